// Round 4
// baseline (1044.214 us; speedup 1.0000x reference)
//
#include <hip/hip_runtime.h>

#define NNODES 50000
#define NEDGES 800000
#define NF 96
#define NF4 (NF / 4)        // 24 float4 per row
#define CHUNK 64            // edges per tile
#define NB 16               // nodes per block (50000 / 16 = 3125 exactly)
#define THREADS 384         // 6 waves
#define MSTRIDE 97          // 96 + 1 pad: read bank = (i + f) % 32, conflict-free

// ---------------------------------------------------------------------------
// Transpose the three 96x96 weight matrices: Wt[k][o] = W[o][k]
// ---------------------------------------------------------------------------
__global__ void transpose_all(const float* __restrict__ We,
                              const float* __restrict__ W1,
                              const float* __restrict__ W2,
                              float* __restrict__ WtE,
                              float* __restrict__ W1t,
                              float* __restrict__ W2t) {
    const float* A;
    float* At;
    if (blockIdx.x == 0)      { A = We; At = WtE; }
    else if (blockIdx.x == 1) { A = W1; At = W1t; }
    else                      { A = W2; At = W2t; }
    for (int i = threadIdx.x; i < NF * NF; i += blockDim.x) {
        int o = i / NF, k = i % NF;
        At[k * NF + o] = A[o * NF + k];
    }
}

// ---------------------------------------------------------------------------
// CSR build: histogram, 3-phase multi-block scan, slot fill (int atomics only)
// ---------------------------------------------------------------------------
__global__ void hist_kernel(const int* __restrict__ ei, int* __restrict__ deg) {
    int e = blockIdx.x * blockDim.x + threadIdx.x;
    if (e < NEDGES) atomicAdd(&deg[ei[NEDGES + e]], 1);
}

#define SCAN_BLOCKS 196  // ceil(50000 / 256)

__global__ __launch_bounds__(256) void scan_partial(const int* __restrict__ deg,
                                                    int* __restrict__ bsum) {
    __shared__ int red[256];
    int t = threadIdx.x;
    int i = blockIdx.x * 256 + t;
    red[t] = (i < NNODES) ? deg[i] : 0;
    __syncthreads();
    for (int off = 128; off; off >>= 1) {
        if (t < off) red[t] += red[t + off];
        __syncthreads();
    }
    if (t == 0) bsum[blockIdx.x] = red[0];
}

__global__ __launch_bounds__(256) void scan_bsum(const int* __restrict__ bsum,
                                                 int* __restrict__ bstart) {
    __shared__ int s[256];
    int t = threadIdx.x;
    s[t] = (t < SCAN_BLOCKS) ? bsum[t] : 0;
    __syncthreads();
    for (int off = 1; off < 256; off <<= 1) {
        int v = (t >= off) ? s[t - off] : 0;
        __syncthreads();
        s[t] += v;
        __syncthreads();
    }
    bstart[t] = (t == 0) ? 0 : s[t - 1];  // exclusive
}

__global__ __launch_bounds__(256) void scan_write(const int* __restrict__ deg,
                                                  const int* __restrict__ bstart,
                                                  int* __restrict__ start,
                                                  int* __restrict__ cursor) {
    __shared__ int s[256];
    int t = threadIdx.x;
    int i = blockIdx.x * 256 + t;
    int d = (i < NNODES) ? deg[i] : 0;
    s[t] = d;
    __syncthreads();
    for (int off = 1; off < 256; off <<= 1) {
        int v = (t >= off) ? s[t - off] : 0;
        __syncthreads();
        s[t] += v;
        __syncthreads();
    }
    int excl = ((t == 0) ? 0 : s[t - 1]) + bstart[blockIdx.x];
    if (i < NNODES) {
        start[i] = excl;
        cursor[i] = excl;
        if (i == NNODES - 1) start[NNODES] = excl + d;
    }
}

// fill: eidx[p] = edge id, srcs[p] = src node
__global__ void fill_kernel(const int* __restrict__ ei, int* __restrict__ cursor,
                            int* __restrict__ eidx, int* __restrict__ srcs) {
    int e = blockIdx.x * blockDim.x + threadIdx.x;
    if (e < NEDGES) {
        int p = atomicAdd(&cursor[ei[NEDGES + e]], 1);
        eidx[p] = e;
        srcs[p] = ei[e];
    }
}

// ---------------------------------------------------------------------------
// Fused edge-GEMM + segment-sum. Block owns NB=16 nodes (CSR range [s0,s1)).
// Per 64-edge chunk:
//   1. lane = one edge: loads its OWN attr row (24 x float4, pipelined groups
//      of 4) -> register GEMM vs wave-uniform s_load weights. No staging LDS,
//      no barriers in this phase.
//   2. + x[src], ReLU -> msg row into LDS M2[edge][feat] (4 x ds_write_b128)
//   3. barrier; fixed-owner threads accumulate their CSR segments; barrier.
// ---------------------------------------------------------------------------
#define KG 4  // float4s per pipeline group; 24/KG = 6 groups
__global__ __launch_bounds__(THREADS) void fused_edge_aggr(
    const float* __restrict__ attr, const int* __restrict__ eidx,
    const int* __restrict__ srcs, const int* __restrict__ start,
    const float* __restrict__ x, const float* __restrict__ Wt,
    const float* __restrict__ be, const float* __restrict__ epsp,
    float* __restrict__ h) {
    __shared__ float M2[CHUNK][MSTRIDE];
    __shared__ int sstart[NB + 1];

    const int t = threadIdx.x;
    const int n0 = blockIdx.x * NB;
    if (t <= NB) sstart[t] = start[n0 + t];
    __syncthreads();
    const int s0 = sstart[0], s1 = sstart[NB];

    const int lane = t & 63;
    const int wv = __builtin_amdgcn_readfirstlane(t >> 6);
    const int ob4 = wv * 4;  // float4 index of this wave's 16-output base
    const float4* Wt4 = reinterpret_cast<const float4*>(Wt);
    const float4* a4 = reinterpret_cast<const float4*>(attr);
    const float4* x4 = reinterpret_cast<const float4*>(x);

    float bias[16];
    {
        const float4* b4 = reinterpret_cast<const float4*>(be);
#pragma unroll
        for (int j = 0; j < 4; ++j) {
            float4 b = b4[ob4 + j];
            bias[4 * j + 0] = b.x; bias[4 * j + 1] = b.y;
            bias[4 * j + 2] = b.z; bias[4 * j + 3] = b.w;
        }
    }

    // register accumulators: thread owns items t, t+384, t+768, t+1152
    float racc[4] = {0.f, 0.f, 0.f, 0.f};

    for (int cl = s0; cl < s1; cl += CHUNK) {
        const int slot = cl + lane;
        const bool valid = slot < s1;
        const int e = valid ? eidx[slot] : eidx[s1 - 1];
        const int src = valid ? srcs[slot] : 0;
        const float4* arow = a4 + (size_t)e * NF4;

        float acc[16];
#pragma unroll
        for (int j = 0; j < 16; ++j) acc[j] = bias[j];

        // ---- register GEMM, 2-deep pipelined over 6 groups of KG float4 ----
        float4 Abuf[2][KG];
#pragma unroll
        for (int j = 0; j < KG; ++j) Abuf[0][j] = arow[j];
#pragma unroll
        for (int g = 0; g < NF4 / KG; ++g) {
            const int cur = g & 1;
            if (g + 1 < NF4 / KG) {
#pragma unroll
                for (int j = 0; j < KG; ++j)
                    Abuf[cur ^ 1][j] = arow[KG * (g + 1) + j];
            }
#pragma unroll
            for (int j = 0; j < KG; ++j) {
                float4 av = Abuf[cur][j];
                const int kb = (g * KG + j) * 4;
#pragma unroll
                for (int c = 0; c < 4; ++c) {
                    float a = (c == 0) ? av.x : (c == 1) ? av.y : (c == 2) ? av.z : av.w;
#pragma unroll
                    for (int q = 0; q < 4; ++q) {
                        float4 w = Wt4[(kb + c) * NF4 + ob4 + q];  // uniform -> s_load
                        acc[4 * q + 0] = fmaf(a, w.x, acc[4 * q + 0]);
                        acc[4 * q + 1] = fmaf(a, w.y, acc[4 * q + 1]);
                        acc[4 * q + 2] = fmaf(a, w.z, acc[4 * q + 2]);
                        acc[4 * q + 3] = fmaf(a, w.w, acc[4 * q + 3]);
                    }
                }
            }
        }

        // ---- + x[src], ReLU, write msg row slice (4 x ds_write_b128) ----
#pragma unroll
        for (int j = 0; j < 4; ++j) {
            float4 xv = x4[(size_t)src * NF4 + ob4 + j];
            float4 m = make_float4(fmaxf(acc[4 * j + 0] + xv.x, 0.f),
                                   fmaxf(acc[4 * j + 1] + xv.y, 0.f),
                                   fmaxf(acc[4 * j + 2] + xv.z, 0.f),
                                   fmaxf(acc[4 * j + 3] + xv.w, 0.f));
            *reinterpret_cast<float4*>(&M2[lane][(ob4 + j) * 4]) = m;
        }
        __syncthreads();

        // ---- segmented accumulate into register cells ----
#pragma unroll
        for (int r = 0; r < 4; ++r) {
            int item = t + THREADS * r;
            int n = item / NF, f = item % NF;
            int segLo = sstart[n] > cl ? sstart[n] : cl;
            int segHi = sstart[n + 1] < cl + CHUNK ? sstart[n + 1] : cl + CHUNK;
            float s = racc[r];
            for (int i = segLo - cl; i < segHi - cl; ++i) s += M2[i][f];
            racc[r] = s;
        }
        __syncthreads();  // done reading M2 before next chunk's writes
    }

    // ---- write h = aggr + (1+eps)*x ----
    const float ep = 1.0f + *epsp;
#pragma unroll
    for (int r = 0; r < 4; ++r) {
        int item = t + THREADS * r;
        int n = n0 + item / NF, f = item % NF;
        h[(size_t)n * NF + f] = fmaf(ep, x[(size_t)n * NF + f], racc[r]);
    }
}

// ---------------------------------------------------------------------------
// Node MLP: out = relu(h @ W1^T + b1) @ W2^T + b2
// ---------------------------------------------------------------------------
#define LDS_STRIDE 65
__global__ __launch_bounds__(THREADS) void node_kernel(
    const float* __restrict__ h,
    const float* __restrict__ W1t, const float* __restrict__ b1,
    const float* __restrict__ W2t, const float* __restrict__ b2,
    float* __restrict__ out) {
    __shared__ float Ht[NF][LDS_STRIDE];
    __shared__ float H1t[NF][LDS_STRIDE];

    const int t = threadIdx.x;
    const int n0 = blockIdx.x * 64;

    const float4* h4 = reinterpret_cast<const float4*>(h);
#pragma unroll
    for (int j = 0; j < 4; ++j) {
        int f4 = t + THREADS * j;
        int n = f4 / NF4, k4 = f4 % NF4;
        float4 v = make_float4(0.f, 0.f, 0.f, 0.f);
        if (n0 + n < NNODES) v = h4[(size_t)(n0 + n) * NF4 + k4];
        Ht[4 * k4 + 0][n] = v.x;
        Ht[4 * k4 + 1][n] = v.y;
        Ht[4 * k4 + 2][n] = v.z;
        Ht[4 * k4 + 3][n] = v.w;
    }
    __syncthreads();

    const int lane = t & 63;
    const int wv = __builtin_amdgcn_readfirstlane(t >> 6);
    const int ob4 = wv * 4;
    const float4* W1t4 = reinterpret_cast<const float4*>(W1t);
    const float4* W2t4 = reinterpret_cast<const float4*>(W2t);
    const float4* b14 = reinterpret_cast<const float4*>(b1);
    const float4* b24 = reinterpret_cast<const float4*>(b2);

    float acc[16];
#pragma unroll
    for (int j = 0; j < 4; ++j) {
        float4 b = b14[ob4 + j];
        acc[4 * j + 0] = b.x; acc[4 * j + 1] = b.y;
        acc[4 * j + 2] = b.z; acc[4 * j + 3] = b.w;
    }
#pragma unroll 8
    for (int k = 0; k < NF; ++k) {
        float a = Ht[k][lane];
#pragma unroll
        for (int j = 0; j < 4; ++j) {
            float4 w = W1t4[k * NF4 + ob4 + j];
            acc[4 * j + 0] = fmaf(a, w.x, acc[4 * j + 0]);
            acc[4 * j + 1] = fmaf(a, w.y, acc[4 * j + 1]);
            acc[4 * j + 2] = fmaf(a, w.z, acc[4 * j + 2]);
            acc[4 * j + 3] = fmaf(a, w.w, acc[4 * j + 3]);
        }
    }
#pragma unroll
    for (int j = 0; j < 16; ++j)
        H1t[wv * 16 + j][lane] = fmaxf(acc[j], 0.0f);
    __syncthreads();

    float acc2[16];
#pragma unroll
    for (int j = 0; j < 4; ++j) {
        float4 b = b24[ob4 + j];
        acc2[4 * j + 0] = b.x; acc2[4 * j + 1] = b.y;
        acc2[4 * j + 2] = b.z; acc2[4 * j + 3] = b.w;
    }
#pragma unroll 8
    for (int k = 0; k < NF; ++k) {
        float a = H1t[k][lane];
#pragma unroll
        for (int j = 0; j < 4; ++j) {
            float4 w = W2t4[k * NF4 + ob4 + j];
            acc2[4 * j + 0] = fmaf(a, w.x, acc2[4 * j + 0]);
            acc2[4 * j + 1] = fmaf(a, w.y, acc2[4 * j + 1]);
            acc2[4 * j + 2] = fmaf(a, w.z, acc2[4 * j + 2]);
            acc2[4 * j + 3] = fmaf(a, w.w, acc2[4 * j + 3]);
        }
    }

    const int n = n0 + lane;
    if (n < NNODES) {
        float4* o4 = reinterpret_cast<float4*>(out) + (size_t)n * NF4;
#pragma unroll
        for (int j = 0; j < 4; ++j)
            o4[ob4 + j] = make_float4(acc2[4 * j + 0], acc2[4 * j + 1],
                                      acc2[4 * j + 2], acc2[4 * j + 3]);
    }
}

// ---------------------------------------------------------------------------
extern "C" void kernel_launch(void* const* d_in, const int* in_sizes, int n_in,
                              void* d_out, int out_size, void* d_ws, size_t ws_size,
                              hipStream_t stream) {
    const float* x   = (const float*)d_in[0];
    const int*   ei  = (const int*)d_in[1];
    const float* ea  = (const float*)d_in[2];
    const float* We  = (const float*)d_in[3];
    const float* be  = (const float*)d_in[4];
    const float* eps = (const float*)d_in[5];
    const float* W1  = (const float*)d_in[6];
    const float* b1  = (const float*)d_in[7];
    const float* W2  = (const float*)d_in[8];
    const float* b2  = (const float*)d_in[9];
    float* out = (float*)d_out;

    // ws layout
    float* h    = (float*)d_ws;                         // 50000*96 f (19.2 MB)
    float* WtE  = h + (size_t)NNODES * NF;              // 3 x 96*96 f
    float* W1t  = WtE + NF * NF;
    float* W2t  = W1t + NF * NF;
    int* deg    = (int*)(W2t + NF * NF);                // 50000
    int* start  = deg + NNODES;                         // 50001
    int* cursor = start + NNODES + 1;                   // 50000
    int* eidx   = cursor + NNODES;                      // 800000
    int* srcs   = eidx + NEDGES;                        // 800000
    int* bsum   = srcs + NEDGES;                        // 256
    int* bstart = bsum + 256;                           // 256

    hipMemsetAsync(deg, 0, NNODES * sizeof(int), stream);
    transpose_all<<<3, 256, 0, stream>>>(We, W1, W2, WtE, W1t, W2t);
    hist_kernel<<<(NEDGES + 255) / 256, 256, 0, stream>>>(ei, deg);
    scan_partial<<<SCAN_BLOCKS, 256, 0, stream>>>(deg, bsum);
    scan_bsum<<<1, 256, 0, stream>>>(bsum, bstart);
    scan_write<<<SCAN_BLOCKS, 256, 0, stream>>>(deg, bstart, start, cursor);
    fill_kernel<<<(NEDGES + 255) / 256, 256, 0, stream>>>(ei, cursor, eidx, srcs);
    fused_edge_aggr<<<NNODES / NB, THREADS, 0, stream>>>(ea, eidx, srcs, start, x,
                                                         WtE, be, eps, h);
    node_kernel<<<(NNODES + 63) / 64, THREADS, 0, stream>>>(h, W1t, b1, W2t, b2, out);
}

// Round 5
// 402.584 us; speedup vs baseline: 2.5938x; 2.5938x over previous
//
#include <hip/hip_runtime.h>

#define NNODES 50000
#define NEDGES 800000
#define NF 96
#define NF4 (NF / 4)        // 24 float4 per f32 row
#define CHUNK 64            // edges per tile
#define NB 16               // nodes per block (50000 / 16 = 3125 exactly)
#define THREADS 384         // 6 waves
#define BSTRIDE 104         // bf16 elems per LDS row (208 B, 16B-aligned rows)
#define MSTRIDE 100         // f32 elems per msg row (400 B, float4-aligned)

typedef short bf16x8 __attribute__((ext_vector_type(8)));
typedef float f32x4 __attribute__((ext_vector_type(4)));

__device__ inline unsigned pk_bf16(float a, float b) {
    union { __bf16 h[2]; unsigned u; } q;
    q.h[0] = (__bf16)a; q.h[1] = (__bf16)b;
    return q.u;
}
__device__ inline unsigned short bf16_1(float a) {
    union { __bf16 h; unsigned short u; } q;
    q.h = (__bf16)a;
    return q.u;
}

// ---------------------------------------------------------------------------
// Prep: W1/W2 f32 transpose (node MLP) + W_edge -> bf16 row-major [o][k]
// ---------------------------------------------------------------------------
__global__ void prep_weights(const float* __restrict__ We,
                             const float* __restrict__ W1,
                             const float* __restrict__ W2,
                             unsigned short* __restrict__ Wb,
                             float* __restrict__ W1t,
                             float* __restrict__ W2t) {
    if (blockIdx.x == 2) {
        for (int i = threadIdx.x; i < NF * NF; i += blockDim.x)
            Wb[i] = bf16_1(We[i]);
        return;
    }
    const float* A = (blockIdx.x == 0) ? W1 : W2;
    float* At = (blockIdx.x == 0) ? W1t : W2t;
    for (int i = threadIdx.x; i < NF * NF; i += blockDim.x) {
        int o = i / NF, k = i % NF;
        At[k * NF + o] = A[o * NF + k];
    }
}

// ---------------------------------------------------------------------------
// CSR build: histogram, 3-phase multi-block scan, slot fill (int atomics only)
// ---------------------------------------------------------------------------
__global__ void hist_kernel(const int* __restrict__ ei, int* __restrict__ deg) {
    int e = blockIdx.x * blockDim.x + threadIdx.x;
    if (e < NEDGES) atomicAdd(&deg[ei[NEDGES + e]], 1);
}

#define SCAN_BLOCKS 196  // ceil(50000 / 256)

__global__ __launch_bounds__(256) void scan_partial(const int* __restrict__ deg,
                                                    int* __restrict__ bsum) {
    __shared__ int red[256];
    int t = threadIdx.x;
    int i = blockIdx.x * 256 + t;
    red[t] = (i < NNODES) ? deg[i] : 0;
    __syncthreads();
    for (int off = 128; off; off >>= 1) {
        if (t < off) red[t] += red[t + off];
        __syncthreads();
    }
    if (t == 0) bsum[blockIdx.x] = red[0];
}

__global__ __launch_bounds__(256) void scan_bsum(const int* __restrict__ bsum,
                                                 int* __restrict__ bstart) {
    __shared__ int s[256];
    int t = threadIdx.x;
    s[t] = (t < SCAN_BLOCKS) ? bsum[t] : 0;
    __syncthreads();
    for (int off = 1; off < 256; off <<= 1) {
        int v = (t >= off) ? s[t - off] : 0;
        __syncthreads();
        s[t] += v;
        __syncthreads();
    }
    bstart[t] = (t == 0) ? 0 : s[t - 1];  // exclusive
}

__global__ __launch_bounds__(256) void scan_write(const int* __restrict__ deg,
                                                  const int* __restrict__ bstart,
                                                  int* __restrict__ start,
                                                  int* __restrict__ cursor) {
    __shared__ int s[256];
    int t = threadIdx.x;
    int i = blockIdx.x * 256 + t;
    int d = (i < NNODES) ? deg[i] : 0;
    s[t] = d;
    __syncthreads();
    for (int off = 1; off < 256; off <<= 1) {
        int v = (t >= off) ? s[t - off] : 0;
        __syncthreads();
        s[t] += v;
        __syncthreads();
    }
    int excl = ((t == 0) ? 0 : s[t - 1]) + bstart[blockIdx.x];
    if (i < NNODES) {
        start[i] = excl;
        cursor[i] = excl;
        if (i == NNODES - 1) start[NNODES] = excl + d;
    }
}

__global__ void fill_kernel(const int* __restrict__ ei, int* __restrict__ cursor,
                            int* __restrict__ eidx, int* __restrict__ srcs) {
    int e = blockIdx.x * blockDim.x + threadIdx.x;
    if (e < NEDGES) {
        int p = atomicAdd(&cursor[ei[NEDGES + e]], 1);
        eidx[p] = e;
        srcs[p] = ei[e];
    }
}

// ---------------------------------------------------------------------------
// Fused edge-GEMM (bf16 MFMA) + segment-sum. Block owns NB=16 nodes.
// Per 64-edge chunk:
//   0. issue srcs + x[src] gather loads (consumed post-MFMA)
//   1. stage attr tile coalesced (24 lanes/row), cvt to bf16, LDS Bt[e][k]
//   2. MFMA: wave w owns output block o=[16w,16w+16); 4 edge-tiles x 3 K-steps
//      A-frag = W rows (registers, hoisted), B-frag = Bt ds_read_b128
//   3. epilogue: + x[src], ReLU -> M2[e][o] (float4)
//   4. fixed-owner segmented reduce from M2 into registers. No float atomics.
// ---------------------------------------------------------------------------
__global__ __launch_bounds__(THREADS) void fused_edge_aggr(
    const float* __restrict__ attr, const int* __restrict__ eidx,
    const int* __restrict__ srcs_g, const int* __restrict__ start,
    const float* __restrict__ x, const unsigned short* __restrict__ Wb,
    const float* __restrict__ be, const float* __restrict__ epsp,
    float* __restrict__ h) {
    __shared__ short Bt[CHUNK][BSTRIDE];   // bf16 attr tile
    __shared__ float M2[CHUNK][MSTRIDE];   // f32 msg tile
    __shared__ int sstart[NB + 1];

    const int t = threadIdx.x;
    const int n0 = blockIdx.x * NB;
    if (t <= NB) sstart[t] = start[n0 + t];
    __syncthreads();
    const int s0 = sstart[0], s1 = sstart[NB];

    const int lane = t & 63;
    const int w = __builtin_amdgcn_readfirstlane(t >> 6);  // wave id 0..5
    const int l15 = lane & 15;
    const int l4 = lane >> 4;  // 0..3

    const float4* a4 = reinterpret_cast<const float4*>(attr);
    const float4* x4 = reinterpret_cast<const float4*>(x);

    // A-fragments: W rows for this wave's o-block, hoisted (L2-hot global).
    // A[m=o][k]: lane holds W[16w + l15][kb*32 + l4*8 + j], j=0..7 (16B)
    bf16x8 af[3];
#pragma unroll
    for (int kb = 0; kb < 3; ++kb)
        af[kb] = *reinterpret_cast<const bf16x8*>(
            Wb + (16 * w + l15) * NF + kb * 32 + l4 * 8);

    // bias for this lane's 4 output rows: o = 16w + l4*4 + r
    const float4 bias4 = reinterpret_cast<const float4*>(be)[w * 4 + l4];
    f32x4 biasv = {bias4.x, bias4.y, bias4.z, bias4.w};

    // register accumulators: thread owns items t, t+384, t+768, t+1152
    float racc[4] = {0.f, 0.f, 0.f, 0.f};

    for (int cl = s0; cl < s1; cl += CHUNK) {
        // ---- 0. issue gather loads early (consumed after MFMA) ----
        int srcv[4];
#pragma unroll
        for (int et = 0; et < 4; ++et) {
            int slot = cl + l15 + 16 * et;
            srcv[et] = srcs_g[slot < s1 ? slot : s1 - 1];
        }
        float4 xv[4];
#pragma unroll
        for (int et = 0; et < 4; ++et)
            xv[et] = x4[(size_t)srcv[et] * NF4 + w * 4 + l4];

        // ---- 1. stage attr tile, cvt bf16, coalesced 24 lanes/row ----
#pragma unroll
        for (int p = 0; p < 4; ++p) {
            int idx = t + THREADS * p;          // 0..1535
            int e = idx / NF4, j = idx % NF4;   // row, float4-col
            int slot = cl + e;
            unsigned lo = 0, hi = 0;
            if (slot < s1) {
                float4 v = a4[(size_t)eidx[slot] * NF4 + j];
                lo = pk_bf16(v.x, v.y);
                hi = pk_bf16(v.z, v.w);
            }
            *reinterpret_cast<uint2*>(&Bt[e][4 * j]) = make_uint2(lo, hi);
        }
        __syncthreads();

        // ---- 2. MFMA: 4 edge-tiles x 3 K-steps ----
        f32x4 acc[4];
#pragma unroll
        for (int et = 0; et < 4; ++et) acc[et] = biasv;
#pragma unroll
        for (int et = 0; et < 4; ++et) {
#pragma unroll
            for (int kb = 0; kb < 3; ++kb) {
                // B[k][n=e]: lane holds Bt[l15 + 16*et][kb*32 + l4*8 + j]
                bf16x8 bf = *reinterpret_cast<const bf16x8*>(
                    &Bt[l15 + 16 * et][kb * 32 + l4 * 8]);
                acc[et] = __builtin_amdgcn_mfma_f32_16x16x32_bf16(
                    af[kb], bf, acc[et], 0, 0, 0);
            }
        }

        // ---- 3. + x[src], ReLU -> M2[e][o] ----
        // D layout: lane holds D[o = l4*4 + r][e = l15] per tile
#pragma unroll
        for (int et = 0; et < 4; ++et) {
            float4 m = make_float4(fmaxf(acc[et][0] + xv[et].x, 0.f),
                                   fmaxf(acc[et][1] + xv[et].y, 0.f),
                                   fmaxf(acc[et][2] + xv[et].z, 0.f),
                                   fmaxf(acc[et][3] + xv[et].w, 0.f));
            *reinterpret_cast<float4*>(&M2[l15 + 16 * et][16 * w + 4 * l4]) = m;
        }
        __syncthreads();

        // ---- 4. segmented accumulate into register cells ----
#pragma unroll
        for (int r = 0; r < 4; ++r) {
            int item = t + THREADS * r;
            int n = item / NF, f = item % NF;
            int segLo = sstart[n] > cl ? sstart[n] : cl;
            int segHi = sstart[n + 1] < cl + CHUNK ? sstart[n + 1] : cl + CHUNK;
            float s = racc[r];
            for (int i = segLo - cl; i < segHi - cl; ++i) s += M2[i][f];
            racc[r] = s;
        }
        __syncthreads();  // M2 + Bt free before next chunk
    }

    // ---- write h = aggr + (1+eps)*x ----
    const float ep = 1.0f + *epsp;
#pragma unroll
    for (int r = 0; r < 4; ++r) {
        int item = t + THREADS * r;
        int n = n0 + item / NF, f = item % NF;
        h[(size_t)n * NF + f] = fmaf(ep, x[(size_t)n * NF + f], racc[r]);
    }
}

// ---------------------------------------------------------------------------
// Node MLP: out = relu(h @ W1^T + b1) @ W2^T + b2   (fp32 VALU)
// ---------------------------------------------------------------------------
#define LDS_STRIDE 65
__global__ __launch_bounds__(THREADS) void node_kernel(
    const float* __restrict__ h,
    const float* __restrict__ W1t, const float* __restrict__ b1,
    const float* __restrict__ W2t, const float* __restrict__ b2,
    float* __restrict__ out) {
    __shared__ float Ht[NF][LDS_STRIDE];
    __shared__ float H1t[NF][LDS_STRIDE];

    const int t = threadIdx.x;
    const int n0 = blockIdx.x * 64;

    const float4* h4 = reinterpret_cast<const float4*>(h);
#pragma unroll
    for (int j = 0; j < 4; ++j) {
        int f4 = t + THREADS * j;
        int n = f4 / NF4, k4 = f4 % NF4;
        float4 v = make_float4(0.f, 0.f, 0.f, 0.f);
        if (n0 + n < NNODES) v = h4[(size_t)(n0 + n) * NF4 + k4];
        Ht[4 * k4 + 0][n] = v.x;
        Ht[4 * k4 + 1][n] = v.y;
        Ht[4 * k4 + 2][n] = v.z;
        Ht[4 * k4 + 3][n] = v.w;
    }
    __syncthreads();

    const int lane = t & 63;
    const int wv = __builtin_amdgcn_readfirstlane(t >> 6);
    const int ob4 = wv * 4;
    const float4* W1t4 = reinterpret_cast<const float4*>(W1t);
    const float4* W2t4 = reinterpret_cast<const float4*>(W2t);
    const float4* b14 = reinterpret_cast<const float4*>(b1);
    const float4* b24 = reinterpret_cast<const float4*>(b2);

    float acc[16];
#pragma unroll
    for (int j = 0; j < 4; ++j) {
        float4 b = b14[ob4 + j];
        acc[4 * j + 0] = b.x; acc[4 * j + 1] = b.y;
        acc[4 * j + 2] = b.z; acc[4 * j + 3] = b.w;
    }
#pragma unroll 8
    for (int k = 0; k < NF; ++k) {
        float a = Ht[k][lane];
#pragma unroll
        for (int j = 0; j < 4; ++j) {
            float4 w = W1t4[k * NF4 + ob4 + j];
            acc[4 * j + 0] = fmaf(a, w.x, acc[4 * j + 0]);
            acc[4 * j + 1] = fmaf(a, w.y, acc[4 * j + 1]);
            acc[4 * j + 2] = fmaf(a, w.z, acc[4 * j + 2]);
            acc[4 * j + 3] = fmaf(a, w.w, acc[4 * j + 3]);
        }
    }
#pragma unroll
    for (int j = 0; j < 16; ++j)
        H1t[wv * 16 + j][lane] = fmaxf(acc[j], 0.0f);
    __syncthreads();

    float acc2[16];
#pragma unroll
    for (int j = 0; j < 4; ++j) {
        float4 b = b24[ob4 + j];
        acc2[4 * j + 0] = b.x; acc2[4 * j + 1] = b.y;
        acc2[4 * j + 2] = b.z; acc2[4 * j + 3] = b.w;
    }
#pragma unroll 8
    for (int k = 0; k < NF; ++k) {
        float a = H1t[k][lane];
#pragma unroll
        for (int j = 0; j < 4; ++j) {
            float4 w = W2t4[k * NF4 + ob4 + j];
            acc2[4 * j + 0] = fmaf(a, w.x, acc2[4 * j + 0]);
            acc2[4 * j + 1] = fmaf(a, w.y, acc2[4 * j + 1]);
            acc2[4 * j + 2] = fmaf(a, w.z, acc2[4 * j + 2]);
            acc2[4 * j + 3] = fmaf(a, w.w, acc2[4 * j + 3]);
        }
    }

    const int n = n0 + lane;
    if (n < NNODES) {
        float4* o4 = reinterpret_cast<float4*>(out) + (size_t)n * NF4;
#pragma unroll
        for (int j = 0; j < 4; ++j)
            o4[ob4 + j] = make_float4(acc2[4 * j + 0], acc2[4 * j + 1],
                                      acc2[4 * j + 2], acc2[4 * j + 3]);
    }
}

// ---------------------------------------------------------------------------
extern "C" void kernel_launch(void* const* d_in, const int* in_sizes, int n_in,
                              void* d_out, int out_size, void* d_ws, size_t ws_size,
                              hipStream_t stream) {
    const float* x   = (const float*)d_in[0];
    const int*   ei  = (const int*)d_in[1];
    const float* ea  = (const float*)d_in[2];
    const float* We  = (const float*)d_in[3];
    const float* be  = (const float*)d_in[4];
    const float* eps = (const float*)d_in[5];
    const float* W1  = (const float*)d_in[6];
    const float* b1  = (const float*)d_in[7];
    const float* W2  = (const float*)d_in[8];
    const float* b2  = (const float*)d_in[9];
    float* out = (float*)d_out;

    // ws layout
    float* h    = (float*)d_ws;                         // 50000*96 f (19.2 MB)
    float* W1t  = h + (size_t)NNODES * NF;              // 96*96 f
    float* W2t  = W1t + NF * NF;                        // 96*96 f
    unsigned short* Wb = (unsigned short*)(W2t + NF * NF);  // 96*96 bf16
    int* deg    = (int*)(Wb + NF * NF);                 // 50000
    int* start  = deg + NNODES;                         // 50001
    int* cursor = start + NNODES + 1;                   // 50000
    int* eidx   = cursor + NNODES;                      // 800000
    int* srcs   = eidx + NEDGES;                        // 800000
    int* bsum   = srcs + NEDGES;                        // 256
    int* bstart = bsum + 256;                           // 256

    hipMemsetAsync(deg, 0, NNODES * sizeof(int), stream);
    prep_weights<<<3, 256, 0, stream>>>(We, W1, W2, Wb, W1t, W2t);
    hist_kernel<<<(NEDGES + 255) / 256, 256, 0, stream>>>(ei, deg);
    scan_partial<<<SCAN_BLOCKS, 256, 0, stream>>>(deg, bsum);
    scan_bsum<<<1, 256, 0, stream>>>(bsum, bstart);
    scan_write<<<SCAN_BLOCKS, 256, 0, stream>>>(deg, bstart, start, cursor);
    fill_kernel<<<(NEDGES + 255) / 256, 256, 0, stream>>>(ei, cursor, eidx, srcs);
    fused_edge_aggr<<<NNODES / NB, THREADS, 0, stream>>>(ea, eidx, srcs, start, x,
                                                         Wb, be, eps, h);
    node_kernel<<<(NNODES + 63) / 64, THREADS, 0, stream>>>(h, W1t, b1, W2t, b2, out);
}